// Round 5
// baseline (268.200 us; speedup 1.0000x reference)
//
#include <hip/hip_runtime.h>
#include <math.h>

#define EPSV 1e-5f

__device__ __forceinline__ float dot4(float4 a, float4 b) {
    return a.x * b.x + a.y * b.y + a.z * b.z + a.w * b.w;
}

// Agent-scope (device-coherent, L2-bypassing) helpers for cross-block exchange.
__device__ __forceinline__ void st_rel(float* p, float v) {
    __hip_atomic_store(p, v, __ATOMIC_RELEASE, __HIP_MEMORY_SCOPE_AGENT);
}
__device__ __forceinline__ float ld_acq(const float* p) {
    return __hip_atomic_load(p, __ATOMIC_ACQUIRE, __HIP_MEMORY_SCOPE_AGENT);
}

// Monotone-counter grid barrier: after the i-th barrier the counter is 128*i.
// Only 4 KB of stat partials cross blocks (via st_rel/ld_acq) — no L2 flush
// needed, unlike cg::grid.sync() (~42 us each, round-3 measurement).
__device__ __forceinline__ void gbar(unsigned* bar, unsigned target) {
    __syncthreads();
    if (threadIdx.x == 0) {
        __hip_atomic_fetch_add(bar, 1u, __ATOMIC_ACQ_REL, __HIP_MEMORY_SCOPE_AGENT);
        while (__hip_atomic_load(bar, __ATOMIC_ACQUIRE, __HIP_MEMORY_SCOPE_AGENT) < target)
            __builtin_amdgcn_s_sleep(1);
    }
    __syncthreads();
}

// ws layout (floats): bar @ 0 (uint), pp1 @ 64 (8x128, [stat][block]),
// pp2 @ 1088 (16x128), pp3 @ 3136 (32x128), pf @ 7232 (128)

__global__ __launch_bounds__(256) void k_fused(
    const float* __restrict__ x_in,
    const float* __restrict__ w1,  const float* __restrict__ b1,
    const float* __restrict__ g1,  const float* __restrict__ be1,
    const float* __restrict__ w2,  const float* __restrict__ b2,
    const float* __restrict__ g2,  const float* __restrict__ be2,
    const float* __restrict__ w3,  const float* __restrict__ b3,
    const float* __restrict__ g3,  const float* __restrict__ be3,
    const float* __restrict__ fc1w, const float* __restrict__ fc1b,
    const float* __restrict__ fc2w, const float* __restrict__ fc2b,
    unsigned* __restrict__ bar,
    float* __restrict__ pp1, float* __restrict__ pp2,
    float* __restrict__ pp3, float* __restrict__ pf,
    float* __restrict__ out)
{
    __shared__ __align__(16) float sxin[1536];   // staged x_in[b]
    __shared__ float sI[784];                    // wireframe
    __shared__ float a1[4 * 784];                // conv1 out
    __shared__ float p1s[4 * 196];               // pool1
    __shared__ float a2[8 * 196];                // conv2 out
    __shared__ float p2s[8 * 49];                // pool2
    __shared__ float a3[16 * 49];                // conv3 out
    __shared__ __align__(16) float sx[1024];     // bn3+relu (zero-padded)
    __shared__ float sh[128];                    // fc1 out
    __shared__ float sw1[36], sw2[288], sw3[1152];
    __shared__ float scs[16], sfs[16];
    __shared__ double sred[32];

    const int tid  = threadIdx.x;
    const int lane = tid & 63;
    const int wv   = tid >> 6;
    const int b    = blockIdx.x;

    // ---- P0: stage inputs ----
    {
        const float4* src = (const float4*)x_in + (size_t)b * 384;
        float4* dst = (float4*)sxin;
        for (int i = tid; i < 384; i += 256) dst[i] = src[i];
    }
    for (int i = tid; i < 784;  i += 256) sI[i]  = 0.0f;
    for (int i = tid; i < 288;  i += 256) sw2[i] = w2[i];
    for (int i = tid; i < 1152; i += 256) sw3[i] = w3[i];
    if (tid < 36) sw1[tid] = w1[tid];
    __syncthreads();

    // ---- P1: wireframe scatter-max (2x2 patch per point; products >= 0) ----
    for (int e = tid; e < 512; e += 256) {
        float p  = sxin[e * 3];
        float tx = sxin[e * 3 + 1] * 28.0f;
        float ty = sxin[e * 3 + 2] * 28.0f;
        int x0 = (int)floorf(tx); float fx = tx - (float)x0;
        int y0 = (int)floorf(ty); float fy = ty - (float)y0;
        float kx[2] = {1.0f - fx, fx};
        float ky[2] = {1.0f - fy, fy};
        #pragma unroll
        for (int dx = 0; dx < 2; ++dx) {
            int gx = x0 + dx;
            if (gx < 0 || gx > 27) continue;
            #pragma unroll
            for (int dy = 0; dy < 2; ++dy) {
                int gy = y0 + dy;
                if (gy < 0 || gy > 27) continue;
                float v = p * (kx[dx] * ky[dy]);
                atomicMax((int*)&sI[gx * 28 + gy], __float_as_int(v));
            }
        }
    }
    __syncthreads();

    // ---- P2: conv1 (wave wv -> channel wv), stats in registers ----
    {
        const float bias = b1[wv];
        float ls = 0.0f, lq = 0.0f;
        for (int p = lane; p < 784; p += 64) {
            int i = p / 28, j = p % 28;
            float s = bias;
            #pragma unroll
            for (int a = 0; a < 3; ++a) {
                int ii = i + a - 1;
                if (ii < 0 || ii > 27) continue;
                #pragma unroll
                for (int c = 0; c < 3; ++c) {
                    int jj = j + c - 1;
                    if (jj < 0 || jj > 27) continue;
                    s += sw1[wv * 9 + a * 3 + c] * sI[ii * 28 + jj];
                }
            }
            a1[wv * 784 + p] = s;
            ls += s; lq += s * s;
        }
        #pragma unroll
        for (int off = 32; off; off >>= 1) {
            ls += __shfl_down(ls, off);
            lq += __shfl_down(lq, off);
        }
        if (lane == 0) {
            st_rel(&pp1[wv * 128 + b],       ls);
            st_rel(&pp1[(4 + wv) * 128 + b], lq);
        }
    }
    gbar(bar, 128);

    // ---- P3: bn1 stats (coalesced, all threads) + bn/relu/pool -> p1s ----
    {
        const int c = tid >> 5, k = tid & 31;
        double t = 0.0;
        #pragma unroll
        for (int j = 0; j < 4; ++j) t += (double)ld_acq(&pp1[c * 128 + k + j * 32]);
        #pragma unroll
        for (int off = 16; off; off >>= 1) t += __shfl_xor(t, off);
        if (k == 0) sred[c] = t;
    }
    __syncthreads();
    if (tid < 4) {
        const double n = 128.0 * 784.0;
        double m = sred[tid] / n;
        double v = sred[4 + tid] / n - m * m;
        float scale = g1[tid] * rsqrtf((float)v + EPSV);
        scs[tid] = scale;
        sfs[tid] = be1[tid] - (float)m * scale;
    }
    __syncthreads();
    for (int idx = tid; idx < 784; idx += 256) {
        int c = idx / 196, pix = idx % 196;
        int r = pix / 14, col = pix % 14;
        const float* yb = a1 + c * 784;
        float scale = scs[c], shift = sfs[c];
        float v00 = yb[(2*r    )*28 + 2*col    ] * scale + shift;
        float v01 = yb[(2*r    )*28 + 2*col + 1] * scale + shift;
        float v10 = yb[(2*r + 1)*28 + 2*col    ] * scale + shift;
        float v11 = yb[(2*r + 1)*28 + 2*col + 1] * scale + shift;
        p1s[idx] = fmaxf(fmaxf(fmaxf(v00, v01), fmaxf(v10, v11)), 0.0f);
    }
    __syncthreads();

    // ---- P4: conv2 (8 groups x 32 lanes) ----
    {
        const int o = tid >> 5, l32 = tid & 31;
        const float bias = b2[o];
        float ls = 0.0f, lq = 0.0f;
        for (int p = l32; p < 196; p += 32) {
            int i = p / 14, j = p % 14;
            float s = bias;
            #pragma unroll
            for (int c = 0; c < 4; ++c) {
                #pragma unroll
                for (int a = 0; a < 3; ++a) {
                    int ii = i + a - 1;
                    if (ii < 0 || ii > 13) continue;
                    #pragma unroll
                    for (int d = 0; d < 3; ++d) {
                        int jj = j + d - 1;
                        if (jj < 0 || jj > 13) continue;
                        s += sw2[((o * 4 + c) * 3 + a) * 3 + d] * p1s[c * 196 + ii * 14 + jj];
                    }
                }
            }
            a2[o * 196 + p] = s;
            ls += s; lq += s * s;
        }
        #pragma unroll
        for (int off = 16; off; off >>= 1) {
            ls += __shfl_xor(ls, off);
            lq += __shfl_xor(lq, off);
        }
        if (l32 == 0) {
            st_rel(&pp2[o * 128 + b],       ls);
            st_rel(&pp2[(8 + o) * 128 + b], lq);
        }
    }
    gbar(bar, 256);

    // ---- P5: bn2 stats + bn/relu/pool -> p2s ----
    {
        const int c = tid >> 4, k = tid & 15;
        double t = 0.0;
        #pragma unroll
        for (int j = 0; j < 8; ++j) t += (double)ld_acq(&pp2[c * 128 + k + j * 16]);
        #pragma unroll
        for (int off = 8; off; off >>= 1) t += __shfl_xor(t, off);
        if (k == 0) sred[c] = t;
    }
    __syncthreads();
    if (tid < 8) {
        const double n = 128.0 * 196.0;
        double m = sred[tid] / n;
        double v = sred[8 + tid] / n - m * m;
        float scale = g2[tid] * rsqrtf((float)v + EPSV);
        scs[tid] = scale;
        sfs[tid] = be2[tid] - (float)m * scale;
    }
    __syncthreads();
    for (int idx = tid; idx < 392; idx += 256) {
        int c = idx / 49, pix = idx % 49;
        int r = pix / 7, col = pix % 7;
        const float* yb = a2 + c * 196;
        float scale = scs[c], shift = sfs[c];
        float v00 = yb[(2*r    )*14 + 2*col    ] * scale + shift;
        float v01 = yb[(2*r    )*14 + 2*col + 1] * scale + shift;
        float v10 = yb[(2*r + 1)*14 + 2*col    ] * scale + shift;
        float v11 = yb[(2*r + 1)*14 + 2*col + 1] * scale + shift;
        p2s[idx] = fmaxf(fmaxf(fmaxf(v00, v01), fmaxf(v10, v11)), 0.0f);
    }
    __syncthreads();

    // ---- P6: conv3 (16 groups x 16 lanes) ----
    {
        const int o = tid >> 4, l16 = tid & 15;
        const float bias = b3[o];
        float ls = 0.0f, lq = 0.0f;
        for (int p = l16; p < 49; p += 16) {
            int i = p / 7, j = p % 7;
            float s = bias;
            #pragma unroll
            for (int c = 0; c < 8; ++c) {
                #pragma unroll
                for (int a = 0; a < 3; ++a) {
                    int ii = i + a - 1;
                    if (ii < 0 || ii > 6) continue;
                    #pragma unroll
                    for (int d = 0; d < 3; ++d) {
                        int jj = j + d - 1;
                        if (jj < 0 || jj > 6) continue;
                        s += sw3[((o * 8 + c) * 3 + a) * 3 + d] * p2s[c * 49 + ii * 7 + jj];
                    }
                }
            }
            a3[o * 49 + p] = s;
            ls += s; lq += s * s;
        }
        #pragma unroll
        for (int off = 8; off; off >>= 1) {
            ls += __shfl_xor(ls, off);
            lq += __shfl_xor(lq, off);
        }
        if (l16 == 0) {
            st_rel(&pp3[o * 128 + b],        ls);
            st_rel(&pp3[(16 + o) * 128 + b], lq);
        }
    }
    gbar(bar, 384);

    // ---- P7: bn3 stats + bn/relu -> sx (padded to 1024 with zeros) ----
    {
        const int c = tid >> 3, k = tid & 7;
        double t = 0.0;
        #pragma unroll
        for (int j = 0; j < 16; ++j) t += (double)ld_acq(&pp3[c * 128 + k + j * 8]);
        #pragma unroll
        for (int off = 4; off; off >>= 1) t += __shfl_xor(t, off);
        if (k == 0) sred[c] = t;
    }
    __syncthreads();
    if (tid < 16) {
        const double n = 128.0 * 49.0;
        double m = sred[tid] / n;
        double v = sred[16 + tid] / n - m * m;
        float scale = g3[tid] * rsqrtf((float)v + EPSV);
        scs[tid] = scale;
        sfs[tid] = be3[tid] - (float)m * scale;
    }
    __syncthreads();
    for (int i = tid; i < 1024; i += 256)
        sx[i] = (i < 784) ? fmaxf(a3[i] * scs[i / 49] + sfs[i / 49], 0.0f) : 0.0f;
    __syncthreads();

    // ---- P8: fc1 — wave wv rows [wv*32, wv*32+32), 4 rows in flight ----
    {
        const float4* xr4 = (const float4*)sx;
        const float4 xa = xr4[lane];
        const float4 xb = xr4[64 + lane];
        const float4 xc = xr4[128 + lane];
        const float4 xd = xr4[192 + lane];       // zeros for lane >= 4
        const int jbase = wv * 32;
        for (int r0 = 0; r0 < 32; r0 += 4) {
            const float4* w0r = (const float4*)(fc1w + (size_t)(jbase + r0    ) * 784);
            const float4* w1r = (const float4*)(fc1w + (size_t)(jbase + r0 + 1) * 784);
            const float4* w2r = (const float4*)(fc1w + (size_t)(jbase + r0 + 2) * 784);
            const float4* w3r = (const float4*)(fc1w + (size_t)(jbase + r0 + 3) * 784);
            float s0 = dot4(w0r[lane], xa) + dot4(w0r[64+lane], xb) + dot4(w0r[128+lane], xc);
            float s1 = dot4(w1r[lane], xa) + dot4(w1r[64+lane], xb) + dot4(w1r[128+lane], xc);
            float s2 = dot4(w2r[lane], xa) + dot4(w2r[64+lane], xb) + dot4(w2r[128+lane], xc);
            float s3 = dot4(w3r[lane], xa) + dot4(w3r[64+lane], xb) + dot4(w3r[128+lane], xc);
            if (lane < 4) {                      // tail floats [768,784)
                s0 += dot4(w0r[192+lane], xd);
                s1 += dot4(w1r[192+lane], xd);
                s2 += dot4(w2r[192+lane], xd);
                s3 += dot4(w3r[192+lane], xd);
            }
            #pragma unroll
            for (int off = 32; off; off >>= 1) {
                s0 += __shfl_xor(s0, off);
                s1 += __shfl_xor(s1, off);
                s2 += __shfl_xor(s2, off);
                s3 += __shfl_xor(s3, off);
            }
            if (lane == 0) {
                sh[jbase + r0    ] = fmaxf(s0 + fc1b[jbase + r0    ], 0.0f);
                sh[jbase + r0 + 1] = fmaxf(s1 + fc1b[jbase + r0 + 1], 0.0f);
                sh[jbase + r0 + 2] = fmaxf(s2 + fc1b[jbase + r0 + 2], 0.0f);
                sh[jbase + r0 + 3] = fmaxf(s3 + fc1b[jbase + r0 + 3], 0.0f);
            }
        }
    }
    __syncthreads();

    // ---- P9: fc2 dot -> pf[b]; arrive at final barrier ----
    if (tid < 64) {
        float v = sh[tid] * fc2w[tid] + sh[tid + 64] * fc2w[tid + 64];
        #pragma unroll
        for (int off = 32; off; off >>= 1) v += __shfl_xor(v, off);
        if (tid == 0) st_rel(&pf[b], v);
    }
    __syncthreads();
    if (tid == 0)
        __hip_atomic_fetch_add(bar, 1u, __ATOMIC_ACQ_REL, __HIP_MEMORY_SCOPE_AGENT);
    if (b != 0) return;

    // ---- P10: block 0 waits for all pf, writes mean ----
    if (tid == 0) {
        while (__hip_atomic_load(bar, __ATOMIC_ACQUIRE, __HIP_MEMORY_SCOPE_AGENT) < 512u)
            __builtin_amdgcn_s_sleep(1);
    }
    __syncthreads();
    if (tid < 64) {
        float v = ld_acq(&pf[tid]) + ld_acq(&pf[tid + 64]);
        #pragma unroll
        for (int off = 32; off; off >>= 1) v += __shfl_xor(v, off);
        if (tid == 0) out[0] = v * (1.0f / 128.0f) + fc2b[0];
    }
}

// ---------------------------------------------------------------------------
extern "C" void kernel_launch(void* const* d_in, const int* in_sizes, int n_in,
                              void* d_out, int out_size, void* d_ws, size_t ws_size,
                              hipStream_t stream) {
    const float* x_in  = (const float*)d_in[0];
    const float* w1    = (const float*)d_in[1];
    const float* b1    = (const float*)d_in[2];
    const float* g1    = (const float*)d_in[3];
    const float* be1   = (const float*)d_in[4];
    const float* w2    = (const float*)d_in[5];
    const float* b2    = (const float*)d_in[6];
    const float* g2    = (const float*)d_in[7];
    const float* be2   = (const float*)d_in[8];
    const float* w3    = (const float*)d_in[9];
    const float* b3    = (const float*)d_in[10];
    const float* g3    = (const float*)d_in[11];
    const float* be3   = (const float*)d_in[12];
    const float* fc1w  = (const float*)d_in[13];
    const float* fc1b  = (const float*)d_in[14];
    const float* fc2w  = (const float*)d_in[15];
    const float* fc2b  = (const float*)d_in[16];

    float* ws  = (float*)d_ws;
    unsigned* bar = (unsigned*)ws;      // [0]
    float* pp1 = ws + 64;               // 8 x 128
    float* pp2 = ws + 1088;             // 16 x 128
    float* pp3 = ws + 3136;             // 32 x 128
    float* pf  = ws + 7232;             // 128
    float* out = (float*)d_out;

    hipMemsetAsync(bar, 0, sizeof(unsigned), stream);

    void* args[] = {
        (void*)&x_in,
        (void*)&w1, (void*)&b1, (void*)&g1, (void*)&be1,
        (void*)&w2, (void*)&b2, (void*)&g2, (void*)&be2,
        (void*)&w3, (void*)&b3, (void*)&g3, (void*)&be3,
        (void*)&fc1w, (void*)&fc1b, (void*)&fc2w, (void*)&fc2b,
        (void*)&bar, (void*)&pp1, (void*)&pp2, (void*)&pp3, (void*)&pf,
        (void*)&out
    };
    hipLaunchKernel((void*)k_fused, dim3(128), dim3(256), args, 0, stream);
}

// Round 6
// 140.233 us; speedup vs baseline: 1.9125x; 1.9125x over previous
//
#include <hip/hip_runtime.h>
#include <math.h>

#define EPSV 1e-5f

__device__ __forceinline__ float dot4(float4 a, float4 b) {
    return a.x * b.x + a.y * b.y + a.z * b.z + a.w * b.w;
}

// RELAXED agent-scope ops: compile to sc1 (L1/L2-bypass, Infinity-Cache
// coherent) accesses with NO buffer_inv / buffer_wbl2 cache maintenance —
// that cache maintenance is what cost rounds 3/5 ~40 us per sync.
__device__ __forceinline__ void st_rlx(float* p, float v) {
    __hip_atomic_store(p, v, __ATOMIC_RELAXED, __HIP_MEMORY_SCOPE_AGENT);
}
__device__ __forceinline__ float ld_rlx(const float* p) {
    return __hip_atomic_load(p, __ATOMIC_RELAXED, __HIP_MEMORY_SCOPE_AGENT);
}
__device__ __forceinline__ void stu_rlx(unsigned* p, unsigned v) {
    __hip_atomic_store(p, v, __ATOMIC_RELAXED, __HIP_MEMORY_SCOPE_AGENT);
}
__device__ __forceinline__ unsigned ldu_rlx(const unsigned* p) {
    return __hip_atomic_load(p, __ATOMIC_RELAXED, __HIP_MEMORY_SCOPE_AGENT);
}

// Flag barrier: block b sets flags[stage*128+b]=magic after draining its
// stores to the coherence point; 128 threads poll the 128 flags in parallel.
// One IF$ round trip (~1-2 us), no L2 invalidate.
__device__ __forceinline__ void gbar(unsigned* flags, int stage, unsigned magic) {
    asm volatile("s_waitcnt vmcnt(0)" ::: "memory");   // own stores visible
    __syncthreads();                                   // all waves drained
    if (threadIdx.x == 0)
        stu_rlx(&flags[(stage << 7) + blockIdx.x], magic);
    if (threadIdx.x < 128) {
        while (ldu_rlx(&flags[(stage << 7) + threadIdx.x]) != magic)
            asm volatile("s_sleep 1" ::: "memory");
    }
    __syncthreads();
}

#define MAGIC0 0x13572468u
#define MAGIC1 0x13572469u
#define MAGIC2 0x1357246Au
#define MAGIC3 0x1357246Bu

// ws layout (4-byte units): flags @ 0 (512), pp1 @ 512 (8x128 [stat][block]),
// pp2 @ 1536 (16x128), pp3 @ 3584 (32x128), pf @ 7680 (128)

__global__ __launch_bounds__(256) void k_fused(
    const float* __restrict__ x_in,
    const float* __restrict__ w1,  const float* __restrict__ b1,
    const float* __restrict__ g1,  const float* __restrict__ be1,
    const float* __restrict__ w2,  const float* __restrict__ b2,
    const float* __restrict__ g2,  const float* __restrict__ be2,
    const float* __restrict__ w3,  const float* __restrict__ b3,
    const float* __restrict__ g3,  const float* __restrict__ be3,
    const float* __restrict__ fc1w, const float* __restrict__ fc1b,
    const float* __restrict__ fc2w, const float* __restrict__ fc2b,
    unsigned* __restrict__ flags,
    float* __restrict__ pp1, float* __restrict__ pp2,
    float* __restrict__ pp3, float* __restrict__ pf,
    float* __restrict__ out)
{
    __shared__ __align__(16) float sxin[1536];   // staged x_in[b]
    __shared__ float sI[784];                    // wireframe
    __shared__ float a1[4 * 784];                // conv1 out
    __shared__ float p1s[4 * 196];               // pool1
    __shared__ float a2[8 * 196];                // conv2 out
    __shared__ float p2s[8 * 49];                // pool2
    __shared__ float a3[16 * 49];                // conv3 out
    __shared__ __align__(16) float sx[1024];     // bn3+relu (zero-padded)
    __shared__ float sh[128];                    // fc1 out
    __shared__ float sw1[36], sw2[288], sw3[1152];
    __shared__ float scs[16], sfs[16];
    __shared__ double sred[32];

    const int tid  = threadIdx.x;
    const int lane = tid & 63;
    const int wv   = tid >> 6;
    const int b    = blockIdx.x;

    // ---- P0: stage inputs ----
    {
        const float4* src = (const float4*)x_in + (size_t)b * 384;
        float4* dst = (float4*)sxin;
        for (int i = tid; i < 384; i += 256) dst[i] = src[i];
    }
    for (int i = tid; i < 784;  i += 256) sI[i]  = 0.0f;
    for (int i = tid; i < 288;  i += 256) sw2[i] = w2[i];
    for (int i = tid; i < 1152; i += 256) sw3[i] = w3[i];
    if (tid < 36) sw1[tid] = w1[tid];
    __syncthreads();

    // ---- P1: wireframe scatter-max (2x2 patch per point; products >= 0) ----
    for (int e = tid; e < 512; e += 256) {
        float p  = sxin[e * 3];
        float tx = sxin[e * 3 + 1] * 28.0f;
        float ty = sxin[e * 3 + 2] * 28.0f;
        int x0 = (int)floorf(tx); float fx = tx - (float)x0;
        int y0 = (int)floorf(ty); float fy = ty - (float)y0;
        float kx[2] = {1.0f - fx, fx};
        float ky[2] = {1.0f - fy, fy};
        #pragma unroll
        for (int dx = 0; dx < 2; ++dx) {
            int gx = x0 + dx;
            if (gx < 0 || gx > 27) continue;
            #pragma unroll
            for (int dy = 0; dy < 2; ++dy) {
                int gy = y0 + dy;
                if (gy < 0 || gy > 27) continue;
                float v = p * (kx[dx] * ky[dy]);
                atomicMax((int*)&sI[gx * 28 + gy], __float_as_int(v));
            }
        }
    }
    __syncthreads();

    // ---- P2: conv1 (wave wv -> channel wv), stats in registers ----
    {
        const float bias = b1[wv];
        float ls = 0.0f, lq = 0.0f;
        for (int p = lane; p < 784; p += 64) {
            int i = p / 28, j = p % 28;
            float s = bias;
            #pragma unroll
            for (int a = 0; a < 3; ++a) {
                int ii = i + a - 1;
                if (ii < 0 || ii > 27) continue;
                #pragma unroll
                for (int c = 0; c < 3; ++c) {
                    int jj = j + c - 1;
                    if (jj < 0 || jj > 27) continue;
                    s += sw1[wv * 9 + a * 3 + c] * sI[ii * 28 + jj];
                }
            }
            a1[wv * 784 + p] = s;
            ls += s; lq += s * s;
        }
        #pragma unroll
        for (int off = 32; off; off >>= 1) {
            ls += __shfl_down(ls, off);
            lq += __shfl_down(lq, off);
        }
        if (lane == 0) {
            st_rlx(&pp1[wv * 128 + b],       ls);
            st_rlx(&pp1[(4 + wv) * 128 + b], lq);
        }
    }
    gbar(flags, 0, MAGIC0);

    // ---- P3: bn1 stats (relaxed coalesced) + bn/relu/pool -> p1s ----
    {
        const int c = tid >> 5, k = tid & 31;
        double t = 0.0;
        #pragma unroll
        for (int j = 0; j < 4; ++j) t += (double)ld_rlx(&pp1[c * 128 + k + j * 32]);
        #pragma unroll
        for (int off = 16; off; off >>= 1) t += __shfl_xor(t, off);
        if (k == 0) sred[c] = t;
    }
    __syncthreads();
    if (tid < 4) {
        const double n = 128.0 * 784.0;
        double m = sred[tid] / n;
        double v = sred[4 + tid] / n - m * m;
        float scale = g1[tid] * rsqrtf((float)v + EPSV);
        scs[tid] = scale;
        sfs[tid] = be1[tid] - (float)m * scale;
    }
    __syncthreads();
    for (int idx = tid; idx < 784; idx += 256) {
        int c = idx / 196, pix = idx % 196;
        int r = pix / 14, col = pix % 14;
        const float* yb = a1 + c * 784;
        float scale = scs[c], shift = sfs[c];
        float v00 = yb[(2*r    )*28 + 2*col    ] * scale + shift;
        float v01 = yb[(2*r    )*28 + 2*col + 1] * scale + shift;
        float v10 = yb[(2*r + 1)*28 + 2*col    ] * scale + shift;
        float v11 = yb[(2*r + 1)*28 + 2*col + 1] * scale + shift;
        p1s[idx] = fmaxf(fmaxf(fmaxf(v00, v01), fmaxf(v10, v11)), 0.0f);
    }
    __syncthreads();

    // ---- P4: conv2 (8 groups x 32 lanes) ----
    {
        const int o = tid >> 5, l32 = tid & 31;
        const float bias = b2[o];
        float ls = 0.0f, lq = 0.0f;
        for (int p = l32; p < 196; p += 32) {
            int i = p / 14, j = p % 14;
            float s = bias;
            #pragma unroll
            for (int c = 0; c < 4; ++c) {
                #pragma unroll
                for (int a = 0; a < 3; ++a) {
                    int ii = i + a - 1;
                    if (ii < 0 || ii > 13) continue;
                    #pragma unroll
                    for (int d = 0; d < 3; ++d) {
                        int jj = j + d - 1;
                        if (jj < 0 || jj > 13) continue;
                        s += sw2[((o * 4 + c) * 3 + a) * 3 + d] * p1s[c * 196 + ii * 14 + jj];
                    }
                }
            }
            a2[o * 196 + p] = s;
            ls += s; lq += s * s;
        }
        #pragma unroll
        for (int off = 16; off; off >>= 1) {
            ls += __shfl_xor(ls, off);
            lq += __shfl_xor(lq, off);
        }
        if (l32 == 0) {
            st_rlx(&pp2[o * 128 + b],       ls);
            st_rlx(&pp2[(8 + o) * 128 + b], lq);
        }
    }
    gbar(flags, 1, MAGIC1);

    // ---- P5: bn2 stats + bn/relu/pool -> p2s ----
    {
        const int c = tid >> 4, k = tid & 15;
        double t = 0.0;
        #pragma unroll
        for (int j = 0; j < 8; ++j) t += (double)ld_rlx(&pp2[c * 128 + k + j * 16]);
        #pragma unroll
        for (int off = 8; off; off >>= 1) t += __shfl_xor(t, off);
        if (k == 0) sred[c] = t;
    }
    __syncthreads();
    if (tid < 8) {
        const double n = 128.0 * 196.0;
        double m = sred[tid] / n;
        double v = sred[8 + tid] / n - m * m;
        float scale = g2[tid] * rsqrtf((float)v + EPSV);
        scs[tid] = scale;
        sfs[tid] = be2[tid] - (float)m * scale;
    }
    __syncthreads();
    for (int idx = tid; idx < 392; idx += 256) {
        int c = idx / 49, pix = idx % 49;
        int r = pix / 7, col = pix % 7;
        const float* yb = a2 + c * 196;
        float scale = scs[c], shift = sfs[c];
        float v00 = yb[(2*r    )*14 + 2*col    ] * scale + shift;
        float v01 = yb[(2*r    )*14 + 2*col + 1] * scale + shift;
        float v10 = yb[(2*r + 1)*14 + 2*col    ] * scale + shift;
        float v11 = yb[(2*r + 1)*14 + 2*col + 1] * scale + shift;
        p2s[idx] = fmaxf(fmaxf(fmaxf(v00, v01), fmaxf(v10, v11)), 0.0f);
    }
    __syncthreads();

    // ---- P6: conv3 (16 groups x 16 lanes) ----
    {
        const int o = tid >> 4, l16 = tid & 15;
        const float bias = b3[o];
        float ls = 0.0f, lq = 0.0f;
        for (int p = l16; p < 49; p += 16) {
            int i = p / 7, j = p % 7;
            float s = bias;
            #pragma unroll
            for (int c = 0; c < 8; ++c) {
                #pragma unroll
                for (int a = 0; a < 3; ++a) {
                    int ii = i + a - 1;
                    if (ii < 0 || ii > 6) continue;
                    #pragma unroll
                    for (int d = 0; d < 3; ++d) {
                        int jj = j + d - 1;
                        if (jj < 0 || jj > 6) continue;
                        s += sw3[((o * 8 + c) * 3 + a) * 3 + d] * p2s[c * 49 + ii * 7 + jj];
                    }
                }
            }
            a3[o * 49 + p] = s;
            ls += s; lq += s * s;
        }
        #pragma unroll
        for (int off = 8; off; off >>= 1) {
            ls += __shfl_xor(ls, off);
            lq += __shfl_xor(lq, off);
        }
        if (l16 == 0) {
            st_rlx(&pp3[o * 128 + b],        ls);
            st_rlx(&pp3[(16 + o) * 128 + b], lq);
        }
    }
    gbar(flags, 2, MAGIC2);

    // ---- P7: bn3 stats + bn/relu -> sx (padded to 1024 with zeros) ----
    {
        const int c = tid >> 3, k = tid & 7;
        double t = 0.0;
        #pragma unroll
        for (int j = 0; j < 16; ++j) t += (double)ld_rlx(&pp3[c * 128 + k + j * 8]);
        #pragma unroll
        for (int off = 4; off; off >>= 1) t += __shfl_xor(t, off);
        if (k == 0) sred[c] = t;
    }
    __syncthreads();
    if (tid < 16) {
        const double n = 128.0 * 49.0;
        double m = sred[tid] / n;
        double v = sred[16 + tid] / n - m * m;
        float scale = g3[tid] * rsqrtf((float)v + EPSV);
        scs[tid] = scale;
        sfs[tid] = be3[tid] - (float)m * scale;
    }
    __syncthreads();
    for (int i = tid; i < 1024; i += 256)
        sx[i] = (i < 784) ? fmaxf(a3[i] * scs[i / 49] + sfs[i / 49], 0.0f) : 0.0f;
    __syncthreads();

    // ---- P8: fc1 — wave wv rows [wv*32, wv*32+32), 4 rows in flight ----
    {
        const float4* xr4 = (const float4*)sx;
        const float4 xa = xr4[lane];
        const float4 xb = xr4[64 + lane];
        const float4 xc = xr4[128 + lane];
        const float4 xd = xr4[192 + lane];       // zeros for lane >= 4
        const int jbase = wv * 32;
        for (int r0 = 0; r0 < 32; r0 += 4) {
            const float4* w0r = (const float4*)(fc1w + (size_t)(jbase + r0    ) * 784);
            const float4* w1r = (const float4*)(fc1w + (size_t)(jbase + r0 + 1) * 784);
            const float4* w2r = (const float4*)(fc1w + (size_t)(jbase + r0 + 2) * 784);
            const float4* w3r = (const float4*)(fc1w + (size_t)(jbase + r0 + 3) * 784);
            float s0 = dot4(w0r[lane], xa) + dot4(w0r[64+lane], xb) + dot4(w0r[128+lane], xc);
            float s1 = dot4(w1r[lane], xa) + dot4(w1r[64+lane], xb) + dot4(w1r[128+lane], xc);
            float s2 = dot4(w2r[lane], xa) + dot4(w2r[64+lane], xb) + dot4(w2r[128+lane], xc);
            float s3 = dot4(w3r[lane], xa) + dot4(w3r[64+lane], xb) + dot4(w3r[128+lane], xc);
            if (lane < 4) {                      // tail floats [768,784)
                s0 += dot4(w0r[192+lane], xd);
                s1 += dot4(w1r[192+lane], xd);
                s2 += dot4(w2r[192+lane], xd);
                s3 += dot4(w3r[192+lane], xd);
            }
            #pragma unroll
            for (int off = 32; off; off >>= 1) {
                s0 += __shfl_xor(s0, off);
                s1 += __shfl_xor(s1, off);
                s2 += __shfl_xor(s2, off);
                s3 += __shfl_xor(s3, off);
            }
            if (lane == 0) {
                sh[jbase + r0    ] = fmaxf(s0 + fc1b[jbase + r0    ], 0.0f);
                sh[jbase + r0 + 1] = fmaxf(s1 + fc1b[jbase + r0 + 1], 0.0f);
                sh[jbase + r0 + 2] = fmaxf(s2 + fc1b[jbase + r0 + 2], 0.0f);
                sh[jbase + r0 + 3] = fmaxf(s3 + fc1b[jbase + r0 + 3], 0.0f);
            }
        }
    }
    __syncthreads();

    // ---- P9: fc2 dot -> pf[b]; signal stage 3 ----
    if (tid < 64) {
        float v = sh[tid] * fc2w[tid] + sh[tid + 64] * fc2w[tid + 64];
        #pragma unroll
        for (int off = 32; off; off >>= 1) v += __shfl_xor(v, off);
        if (tid == 0) st_rlx(&pf[b], v);
    }
    asm volatile("s_waitcnt vmcnt(0)" ::: "memory");
    __syncthreads();
    if (tid == 0) stu_rlx(&flags[(3 << 7) + b], MAGIC3);
    if (b != 0) return;

    // ---- P10: block 0 waits for all pf, writes mean ----
    if (tid < 128) {
        while (ldu_rlx(&flags[(3 << 7) + tid]) != MAGIC3)
            asm volatile("s_sleep 1" ::: "memory");
    }
    __syncthreads();
    if (tid < 64) {
        float v = ld_rlx(&pf[tid]) + ld_rlx(&pf[tid + 64]);
        #pragma unroll
        for (int off = 32; off; off >>= 1) v += __shfl_xor(v, off);
        if (tid == 0) out[0] = v * (1.0f / 128.0f) + fc2b[0];
    }
}

// ---------------------------------------------------------------------------
extern "C" void kernel_launch(void* const* d_in, const int* in_sizes, int n_in,
                              void* d_out, int out_size, void* d_ws, size_t ws_size,
                              hipStream_t stream) {
    const float* x_in  = (const float*)d_in[0];
    const float* w1    = (const float*)d_in[1];
    const float* b1    = (const float*)d_in[2];
    const float* g1    = (const float*)d_in[3];
    const float* be1   = (const float*)d_in[4];
    const float* w2    = (const float*)d_in[5];
    const float* b2    = (const float*)d_in[6];
    const float* g2    = (const float*)d_in[7];
    const float* be2   = (const float*)d_in[8];
    const float* w3    = (const float*)d_in[9];
    const float* b3    = (const float*)d_in[10];
    const float* g3    = (const float*)d_in[11];
    const float* be3   = (const float*)d_in[12];
    const float* fc1w  = (const float*)d_in[13];
    const float* fc1b  = (const float*)d_in[14];
    const float* fc2w  = (const float*)d_in[15];
    const float* fc2b  = (const float*)d_in[16];

    float* ws  = (float*)d_ws;
    unsigned* flags = (unsigned*)ws;    // 512 (4 stages x 128 blocks)
    float* pp1 = ws + 512;              // 8 x 128
    float* pp2 = ws + 1536;             // 16 x 128
    float* pp3 = ws + 3584;             // 32 x 128
    float* pf  = ws + 7680;             // 128
    float* out = (float*)d_out;

    hipMemsetAsync(flags, 0, 512 * sizeof(unsigned), stream);

    void* args[] = {
        (void*)&x_in,
        (void*)&w1, (void*)&b1, (void*)&g1, (void*)&be1,
        (void*)&w2, (void*)&b2, (void*)&g2, (void*)&be2,
        (void*)&w3, (void*)&b3, (void*)&g3, (void*)&be3,
        (void*)&fc1w, (void*)&fc1b, (void*)&fc2w, (void*)&fc2b,
        (void*)&flags, (void*)&pp1, (void*)&pp2, (void*)&pp3, (void*)&pf,
        (void*)&out
    };
    hipLaunchKernel((void*)k_fused, dim3(128), dim3(256), args, 0, stream);
}

// Round 7
// 139.656 us; speedup vs baseline: 1.9204x; 1.0041x over previous
//
#include <hip/hip_runtime.h>
#include <math.h>

#define EPSV 1e-5f

__device__ __forceinline__ float dot4(float4 a, float4 b) {
    return a.x * b.x + a.y * b.y + a.z * b.z + a.w * b.w;
}

// RELAXED agent-scope ops: sc1 path, coherent at the Infinity Cache, and —
// critically — no buffer_inv / buffer_wbl2 cache maintenance (ACQ_REL
// lowering cost rounds 3/4/5 ~35 us per sync point; round 6 verified
// correctness of the relaxed path end-to-end, absmax 0.0).
__device__ __forceinline__ void st_rlx(float* p, float v) {
    __hip_atomic_store(p, v, __ATOMIC_RELAXED, __HIP_MEMORY_SCOPE_AGENT);
}
__device__ __forceinline__ float ld_rlx(const float* p) {
    return __hip_atomic_load(p, __ATOMIC_RELAXED, __HIP_MEMORY_SCOPE_AGENT);
}

// Single-counter grid barrier, all-relaxed. Producer stores are drained to
// the coherence point by vmcnt(0) BEFORE the arrival add, so a consumer that
// observes count>=target may safely read producers' sc1 data with relaxed
// loads. One poller thread per block (128 total pollers on one IF$ line)
// instead of round 6's 16K threads x 128 lines.
__device__ __forceinline__ void gbar(unsigned* bar, unsigned target) {
    asm volatile("s_waitcnt vmcnt(0)" ::: "memory");   // drain own sc1 stores
    __syncthreads();                                   // all waves drained
    if (threadIdx.x == 0) {
        __hip_atomic_fetch_add(bar, 1u, __ATOMIC_RELAXED, __HIP_MEMORY_SCOPE_AGENT);
        while (__hip_atomic_load(bar, __ATOMIC_RELAXED, __HIP_MEMORY_SCOPE_AGENT) < target)
            __builtin_amdgcn_s_sleep(2);
    }
    __syncthreads();
}

// ws layout (4-byte units): bar @ 0, pp1 @ 64 (8x128 [stat][block]),
// pp2 @ 1088 (16x128), pp3 @ 3136 (32x128), pf @ 7232 (128)

__global__ __launch_bounds__(256) void k_fused(
    const float* __restrict__ x_in,
    const float* __restrict__ w1,  const float* __restrict__ b1,
    const float* __restrict__ g1,  const float* __restrict__ be1,
    const float* __restrict__ w2,  const float* __restrict__ b2,
    const float* __restrict__ g2,  const float* __restrict__ be2,
    const float* __restrict__ w3,  const float* __restrict__ b3,
    const float* __restrict__ g3,  const float* __restrict__ be3,
    const float* __restrict__ fc1w, const float* __restrict__ fc1b,
    const float* __restrict__ fc2w, const float* __restrict__ fc2b,
    unsigned* __restrict__ bar,
    float* __restrict__ pp1, float* __restrict__ pp2,
    float* __restrict__ pp3, float* __restrict__ pf,
    float* __restrict__ out)
{
    __shared__ __align__(16) float sxin[1536];   // staged x_in[b]
    __shared__ float sI[784];                    // wireframe
    __shared__ float a1[4 * 784];                // conv1 out
    __shared__ float p1s[4 * 196];               // pool1
    __shared__ float a2[8 * 196];                // conv2 out
    __shared__ float p2s[8 * 49];                // pool2
    __shared__ float a3[16 * 49];                // conv3 out
    __shared__ __align__(16) float sx[1024];     // bn3+relu (zero-padded)
    __shared__ float sh[128];                    // fc1 out
    __shared__ float sw1[36], sw2[288], sw3[1152];
    __shared__ float scs[16], sfs[16];
    __shared__ double sred[32];

    const int tid  = threadIdx.x;
    const int lane = tid & 63;
    const int wv   = tid >> 6;
    const int b    = blockIdx.x;

    // ---- P0: stage inputs ----
    {
        const float4* src = (const float4*)x_in + (size_t)b * 384;
        float4* dst = (float4*)sxin;
        for (int i = tid; i < 384; i += 256) dst[i] = src[i];
    }
    for (int i = tid; i < 784;  i += 256) sI[i]  = 0.0f;
    for (int i = tid; i < 288;  i += 256) sw2[i] = w2[i];
    for (int i = tid; i < 1152; i += 256) sw3[i] = w3[i];
    if (tid < 36) sw1[tid] = w1[tid];
    __syncthreads();

    // ---- P1: wireframe scatter-max (2x2 patch per point; products >= 0) ----
    for (int e = tid; e < 512; e += 256) {
        float p  = sxin[e * 3];
        float tx = sxin[e * 3 + 1] * 28.0f;
        float ty = sxin[e * 3 + 2] * 28.0f;
        int x0 = (int)floorf(tx); float fx = tx - (float)x0;
        int y0 = (int)floorf(ty); float fy = ty - (float)y0;
        float kx[2] = {1.0f - fx, fx};
        float ky[2] = {1.0f - fy, fy};
        #pragma unroll
        for (int dx = 0; dx < 2; ++dx) {
            int gx = x0 + dx;
            if (gx < 0 || gx > 27) continue;
            #pragma unroll
            for (int dy = 0; dy < 2; ++dy) {
                int gy = y0 + dy;
                if (gy < 0 || gy > 27) continue;
                float v = p * (kx[dx] * ky[dy]);
                atomicMax((int*)&sI[gx * 28 + gy], __float_as_int(v));
            }
        }
    }
    __syncthreads();

    // ---- P2: conv1 (wave wv -> channel wv), stats in registers ----
    {
        const float bias = b1[wv];
        float ls = 0.0f, lq = 0.0f;
        for (int p = lane; p < 784; p += 64) {
            int i = p / 28, j = p % 28;
            float s = bias;
            #pragma unroll
            for (int a = 0; a < 3; ++a) {
                int ii = i + a - 1;
                if (ii < 0 || ii > 27) continue;
                #pragma unroll
                for (int c = 0; c < 3; ++c) {
                    int jj = j + c - 1;
                    if (jj < 0 || jj > 27) continue;
                    s += sw1[wv * 9 + a * 3 + c] * sI[ii * 28 + jj];
                }
            }
            a1[wv * 784 + p] = s;
            ls += s; lq += s * s;
        }
        #pragma unroll
        for (int off = 32; off; off >>= 1) {
            ls += __shfl_down(ls, off);
            lq += __shfl_down(lq, off);
        }
        if (lane == 0) {
            st_rlx(&pp1[wv * 128 + b],       ls);
            st_rlx(&pp1[(4 + wv) * 128 + b], lq);
        }
    }
    gbar(bar, 128);

    // ---- P3: bn1 stats (relaxed coalesced) + bn/relu/pool -> p1s ----
    {
        const int c = tid >> 5, k = tid & 31;
        double t = 0.0;
        #pragma unroll
        for (int j = 0; j < 4; ++j) t += (double)ld_rlx(&pp1[c * 128 + k + j * 32]);
        #pragma unroll
        for (int off = 16; off; off >>= 1) t += __shfl_xor(t, off);
        if (k == 0) sred[c] = t;
    }
    __syncthreads();
    if (tid < 4) {
        const double n = 128.0 * 784.0;
        double m = sred[tid] / n;
        double v = sred[4 + tid] / n - m * m;
        float scale = g1[tid] * rsqrtf((float)v + EPSV);
        scs[tid] = scale;
        sfs[tid] = be1[tid] - (float)m * scale;
    }
    __syncthreads();
    for (int idx = tid; idx < 784; idx += 256) {
        int c = idx / 196, pix = idx % 196;
        int r = pix / 14, col = pix % 14;
        const float* yb = a1 + c * 784;
        float scale = scs[c], shift = sfs[c];
        float v00 = yb[(2*r    )*28 + 2*col    ] * scale + shift;
        float v01 = yb[(2*r    )*28 + 2*col + 1] * scale + shift;
        float v10 = yb[(2*r + 1)*28 + 2*col    ] * scale + shift;
        float v11 = yb[(2*r + 1)*28 + 2*col + 1] * scale + shift;
        p1s[idx] = fmaxf(fmaxf(fmaxf(v00, v01), fmaxf(v10, v11)), 0.0f);
    }
    __syncthreads();

    // ---- P4: conv2 (8 groups x 32 lanes) ----
    {
        const int o = tid >> 5, l32 = tid & 31;
        const float bias = b2[o];
        float ls = 0.0f, lq = 0.0f;
        for (int p = l32; p < 196; p += 32) {
            int i = p / 14, j = p % 14;
            float s = bias;
            #pragma unroll
            for (int c = 0; c < 4; ++c) {
                #pragma unroll
                for (int a = 0; a < 3; ++a) {
                    int ii = i + a - 1;
                    if (ii < 0 || ii > 13) continue;
                    #pragma unroll
                    for (int d = 0; d < 3; ++d) {
                        int jj = j + d - 1;
                        if (jj < 0 || jj > 13) continue;
                        s += sw2[((o * 4 + c) * 3 + a) * 3 + d] * p1s[c * 196 + ii * 14 + jj];
                    }
                }
            }
            a2[o * 196 + p] = s;
            ls += s; lq += s * s;
        }
        #pragma unroll
        for (int off = 16; off; off >>= 1) {
            ls += __shfl_xor(ls, off);
            lq += __shfl_xor(lq, off);
        }
        if (l32 == 0) {
            st_rlx(&pp2[o * 128 + b],       ls);
            st_rlx(&pp2[(8 + o) * 128 + b], lq);
        }
    }
    gbar(bar, 256);

    // ---- P5: bn2 stats + bn/relu/pool -> p2s ----
    {
        const int c = tid >> 4, k = tid & 15;
        double t = 0.0;
        #pragma unroll
        for (int j = 0; j < 8; ++j) t += (double)ld_rlx(&pp2[c * 128 + k + j * 16]);
        #pragma unroll
        for (int off = 8; off; off >>= 1) t += __shfl_xor(t, off);
        if (k == 0) sred[c] = t;
    }
    __syncthreads();
    if (tid < 8) {
        const double n = 128.0 * 196.0;
        double m = sred[tid] / n;
        double v = sred[8 + tid] / n - m * m;
        float scale = g2[tid] * rsqrtf((float)v + EPSV);
        scs[tid] = scale;
        sfs[tid] = be2[tid] - (float)m * scale;
    }
    __syncthreads();
    for (int idx = tid; idx < 392; idx += 256) {
        int c = idx / 49, pix = idx % 49;
        int r = pix / 7, col = pix % 7;
        const float* yb = a2 + c * 196;
        float scale = scs[c], shift = sfs[c];
        float v00 = yb[(2*r    )*14 + 2*col    ] * scale + shift;
        float v01 = yb[(2*r    )*14 + 2*col + 1] * scale + shift;
        float v10 = yb[(2*r + 1)*14 + 2*col    ] * scale + shift;
        float v11 = yb[(2*r + 1)*14 + 2*col + 1] * scale + shift;
        p2s[idx] = fmaxf(fmaxf(fmaxf(v00, v01), fmaxf(v10, v11)), 0.0f);
    }
    __syncthreads();

    // ---- P6: conv3 (16 groups x 16 lanes) ----
    {
        const int o = tid >> 4, l16 = tid & 15;
        const float bias = b3[o];
        float ls = 0.0f, lq = 0.0f;
        for (int p = l16; p < 49; p += 16) {
            int i = p / 7, j = p % 7;
            float s = bias;
            #pragma unroll
            for (int c = 0; c < 8; ++c) {
                #pragma unroll
                for (int a = 0; a < 3; ++a) {
                    int ii = i + a - 1;
                    if (ii < 0 || ii > 6) continue;
                    #pragma unroll
                    for (int d = 0; d < 3; ++d) {
                        int jj = j + d - 1;
                        if (jj < 0 || jj > 6) continue;
                        s += sw3[((o * 8 + c) * 3 + a) * 3 + d] * p2s[c * 49 + ii * 7 + jj];
                    }
                }
            }
            a3[o * 49 + p] = s;
            ls += s; lq += s * s;
        }
        #pragma unroll
        for (int off = 8; off; off >>= 1) {
            ls += __shfl_xor(ls, off);
            lq += __shfl_xor(lq, off);
        }
        if (l16 == 0) {
            st_rlx(&pp3[o * 128 + b],        ls);
            st_rlx(&pp3[(16 + o) * 128 + b], lq);
        }
    }
    gbar(bar, 384);

    // ---- P7: bn3 stats + bn/relu -> sx (padded to 1024 with zeros) ----
    {
        const int c = tid >> 3, k = tid & 7;
        double t = 0.0;
        #pragma unroll
        for (int j = 0; j < 16; ++j) t += (double)ld_rlx(&pp3[c * 128 + k + j * 8]);
        #pragma unroll
        for (int off = 4; off; off >>= 1) t += __shfl_xor(t, off);
        if (k == 0) sred[c] = t;
    }
    __syncthreads();
    if (tid < 16) {
        const double n = 128.0 * 49.0;
        double m = sred[tid] / n;
        double v = sred[16 + tid] / n - m * m;
        float scale = g3[tid] * rsqrtf((float)v + EPSV);
        scs[tid] = scale;
        sfs[tid] = be3[tid] - (float)m * scale;
    }
    __syncthreads();
    for (int i = tid; i < 1024; i += 256)
        sx[i] = (i < 784) ? fmaxf(a3[i] * scs[i / 49] + sfs[i / 49], 0.0f) : 0.0f;
    __syncthreads();

    // ---- P8: fc1 — wave wv rows [wv*32, wv*32+32), 4 rows in flight ----
    {
        const float4* xr4 = (const float4*)sx;
        const float4 xa = xr4[lane];
        const float4 xb = xr4[64 + lane];
        const float4 xc = xr4[128 + lane];
        const float4 xd = xr4[192 + lane];       // zeros for lane >= 4
        const int jbase = wv * 32;
        for (int r0 = 0; r0 < 32; r0 += 4) {
            const float4* w0r = (const float4*)(fc1w + (size_t)(jbase + r0    ) * 784);
            const float4* w1r = (const float4*)(fc1w + (size_t)(jbase + r0 + 1) * 784);
            const float4* w2r = (const float4*)(fc1w + (size_t)(jbase + r0 + 2) * 784);
            const float4* w3r = (const float4*)(fc1w + (size_t)(jbase + r0 + 3) * 784);
            float s0 = dot4(w0r[lane], xa) + dot4(w0r[64+lane], xb) + dot4(w0r[128+lane], xc);
            float s1 = dot4(w1r[lane], xa) + dot4(w1r[64+lane], xb) + dot4(w1r[128+lane], xc);
            float s2 = dot4(w2r[lane], xa) + dot4(w2r[64+lane], xb) + dot4(w2r[128+lane], xc);
            float s3 = dot4(w3r[lane], xa) + dot4(w3r[64+lane], xb) + dot4(w3r[128+lane], xc);
            if (lane < 4) {                      // tail floats [768,784)
                s0 += dot4(w0r[192+lane], xd);
                s1 += dot4(w1r[192+lane], xd);
                s2 += dot4(w2r[192+lane], xd);
                s3 += dot4(w3r[192+lane], xd);
            }
            #pragma unroll
            for (int off = 32; off; off >>= 1) {
                s0 += __shfl_xor(s0, off);
                s1 += __shfl_xor(s1, off);
                s2 += __shfl_xor(s2, off);
                s3 += __shfl_xor(s3, off);
            }
            if (lane == 0) {
                sh[jbase + r0    ] = fmaxf(s0 + fc1b[jbase + r0    ], 0.0f);
                sh[jbase + r0 + 1] = fmaxf(s1 + fc1b[jbase + r0 + 1], 0.0f);
                sh[jbase + r0 + 2] = fmaxf(s2 + fc1b[jbase + r0 + 2], 0.0f);
                sh[jbase + r0 + 3] = fmaxf(s3 + fc1b[jbase + r0 + 3], 0.0f);
            }
        }
    }
    __syncthreads();

    // ---- P9: fc2 dot -> pf[b]; arrive (counter -> 512) ----
    if (tid < 64) {
        float v = sh[tid] * fc2w[tid] + sh[tid + 64] * fc2w[tid + 64];
        #pragma unroll
        for (int off = 32; off; off >>= 1) v += __shfl_xor(v, off);
        if (tid == 0) st_rlx(&pf[b], v);
    }
    asm volatile("s_waitcnt vmcnt(0)" ::: "memory");
    __syncthreads();
    if (tid == 0)
        __hip_atomic_fetch_add(bar, 1u, __ATOMIC_RELAXED, __HIP_MEMORY_SCOPE_AGENT);
    if (b != 0) return;

    // ---- P10: block 0 waits for all pf, writes mean ----
    if (tid == 0) {
        while (__hip_atomic_load(bar, __ATOMIC_RELAXED, __HIP_MEMORY_SCOPE_AGENT) < 512u)
            __builtin_amdgcn_s_sleep(2);
    }
    __syncthreads();
    if (tid < 64) {
        float v = ld_rlx(&pf[tid]) + ld_rlx(&pf[tid + 64]);
        #pragma unroll
        for (int off = 32; off; off >>= 1) v += __shfl_xor(v, off);
        if (tid == 0) out[0] = v * (1.0f / 128.0f) + fc2b[0];
    }
}

// ---------------------------------------------------------------------------
extern "C" void kernel_launch(void* const* d_in, const int* in_sizes, int n_in,
                              void* d_out, int out_size, void* d_ws, size_t ws_size,
                              hipStream_t stream) {
    const float* x_in  = (const float*)d_in[0];
    const float* w1    = (const float*)d_in[1];
    const float* b1    = (const float*)d_in[2];
    const float* g1    = (const float*)d_in[3];
    const float* be1   = (const float*)d_in[4];
    const float* w2    = (const float*)d_in[5];
    const float* b2    = (const float*)d_in[6];
    const float* g2    = (const float*)d_in[7];
    const float* be2   = (const float*)d_in[8];
    const float* w3    = (const float*)d_in[9];
    const float* b3    = (const float*)d_in[10];
    const float* g3    = (const float*)d_in[11];
    const float* be3   = (const float*)d_in[12];
    const float* fc1w  = (const float*)d_in[13];
    const float* fc1b  = (const float*)d_in[14];
    const float* fc2w  = (const float*)d_in[15];
    const float* fc2b  = (const float*)d_in[16];

    float* ws  = (float*)d_ws;
    unsigned* bar = (unsigned*)ws;      // [0]
    float* pp1 = ws + 64;               // 8 x 128
    float* pp2 = ws + 1088;             // 16 x 128
    float* pp3 = ws + 3136;             // 32 x 128
    float* pf  = ws + 7232;             // 128
    float* out = (float*)d_out;

    hipMemsetAsync(bar, 0, sizeof(unsigned), stream);

    void* args[] = {
        (void*)&x_in,
        (void*)&w1, (void*)&b1, (void*)&g1, (void*)&be1,
        (void*)&w2, (void*)&b2, (void*)&g2, (void*)&be2,
        (void*)&w3, (void*)&b3, (void*)&g3, (void*)&be3,
        (void*)&fc1w, (void*)&fc1b, (void*)&fc2w, (void*)&fc2b,
        (void*)&bar, (void*)&pp1, (void*)&pp2, (void*)&pp3, (void*)&pf,
        (void*)&out
    };
    hipLaunchKernel((void*)k_fused, dim3(128), dim3(256), args, 0, stream);
}